// Round 19
// baseline (178.037 us; speedup 1.0000x reference)
//
#include <hip/hip_runtime.h>

#define T_DIM 16384
#define D_DIM 2048
#define GHD   128
#define W_DIM 4
#define B_DIM 8

typedef _Float16 f16x8 __attribute__((ext_vector_type(8)));
typedef float    f32x4 __attribute__((ext_vector_type(4)));

// workspace layout (bytes)
#define WS_W1F  0
#define WS_W2F  (512*1024)
#define WS_B2T  (WS_W2F + 2*1024*1024)
#define WS_HLIN (WS_B2T + 32*1024)

// ---------------------------------------------------------------------------
// prep: coalesced via LDS-staged transpose (unchanged).
// ---------------------------------------------------------------------------
__global__ __launch_bounds__(256) void prep_kernel(
    const float* __restrict__ w1, const float* __restrict__ w2,
    const float* __restrict__ b2, _Float16* __restrict__ w1f,
    _Float16* __restrict__ w2f, float* __restrict__ b2t) {
  __shared__ float sm[4096];
  int bid = blockIdx.x, tid = threadIdx.x;
  int lane = tid & 63;
  int g = lane >> 4, c = lane & 15;

  if (bid < 512) {                       // ---- W2F ----
    int df = bid >> 2, kk = bid & 3;
#pragma unroll
    for (int q = 0; q < 8; ++q) {
      int li = q * 256 + tid;
      int kl = li >> 6, nl = li & 63;
      sm[li] = w2[(size_t)(32 * kk + kl) * (D_DIM * W_DIM) + 64 * df + nl];
    }
    __syncthreads();
    int w = tid >> 6;
    f16x8 v;
#pragma unroll
    for (int i = 0; i < 8; ++i)
      v[i] = (_Float16)sm[(8 * g + i) * 64 + 4 * c + w];
    int fid = (w * 128 + df) * 4 + kk;
    *reinterpret_cast<f16x8*>(w2f + ((size_t)fid * 64 + lane) * 8) = v;
  } else if (bid < 576) {                // ---- W1F ----
    int kk = bid - 512;
#pragma unroll
    for (int q = 0; q < 16; ++q) {
      int li = q * 256 + tid;
      int kl = li >> 7, nl = li & 127;
      sm[li] = w1[(32 * kk + kl) * GHD + nl];
    }
    __syncthreads();
#pragma unroll
    for (int h = 0; h < 2; ++h) {
      int nf = (tid >> 6) * 2 + h;
      f16x8 v;
#pragma unroll
      for (int i = 0; i < 8; ++i)
        v[i] = (_Float16)sm[(8 * g + i) * GHD + 16 * nf + c];
      *reinterpret_cast<f16x8*>(w1f + ((size_t)(kk * 8 + nf) * 64 + lane) * 8) = v;
    }
  } else {                               // ---- B2T ----
#pragma unroll
    for (int q = 0; q < 4; ++q) {
      int e = (bid - 576) * 1024 + q * 256 + tid;
      int w = e >> 11, d = e & 2047;
      b2t[w * D_DIM + d] = b2[d * 4 + w];
    }
  }
}

// ---------------------------------------------------------------------------
// gemm1 v2 (measured win): k-split across waves; gen loaded once per block;
// LDS reduce red[nf][wv][lane].
// ---------------------------------------------------------------------------
__global__ __launch_bounds__(256) void gemm1_kernel(
    const float* __restrict__ gen, const _Float16* __restrict__ w1f,
    _Float16* __restrict__ hlin) {
  __shared__ f32x4 red[8][4][64];
  int tid = threadIdx.x;
  int lane = tid & 63, wv = tid >> 6;
  int g = lane >> 4, c = lane & 15;
  int row = blockIdx.x * 16 + c;
  const float* arow = gen + (size_t)row * D_DIM;

  f32x4 acc[8];
#pragma unroll
  for (int nf = 0; nf < 8; ++nf) acc[nf] = f32x4{0.f, 0.f, 0.f, 0.f};

  for (int it = 0; it < 16; ++it) {
    int kk = 16 * wv + it;
    float4 a0 = *reinterpret_cast<const float4*>(arow + kk * 32 + 8 * g);
    float4 a1 = *reinterpret_cast<const float4*>(arow + kk * 32 + 8 * g + 4);
    f16x8 af;
    af[0] = (_Float16)a0.x; af[1] = (_Float16)a0.y;
    af[2] = (_Float16)a0.z; af[3] = (_Float16)a0.w;
    af[4] = (_Float16)a1.x; af[5] = (_Float16)a1.y;
    af[6] = (_Float16)a1.z; af[7] = (_Float16)a1.w;
#pragma unroll
    for (int nf = 0; nf < 8; ++nf) {
      f16x8 b = *reinterpret_cast<const f16x8*>(
          w1f + ((size_t)(kk * 8 + nf) * 64 + lane) * 8);
      acc[nf] = __builtin_amdgcn_mfma_f32_16x16x32_f16(af, b, acc[nf], 0, 0, 0);
    }
  }

#pragma unroll
  for (int nf = 0; nf < 8; ++nf) red[nf][wv][lane] = acc[nf];
  __syncthreads();

  int trow = blockIdx.x * 16 + 4 * g;
#pragma unroll
  for (int h = 0; h < 2; ++h) {
    int nf = 2 * wv + h;
    f32x4 s0 = red[nf][0][lane];
    f32x4 s1 = red[nf][1][lane];
    f32x4 s2 = red[nf][2][lane];
    f32x4 s3 = red[nf][3][lane];
    f32x4 s;
#pragma unroll
    for (int r = 0; r < 4; ++r) s[r] = (s0[r] + s1[r]) + (s2[r] + s3[r]);
#pragma unroll
    for (int r = 0; r < 4; ++r) {
      float v = s[r];
      hlin[(size_t)(trow + r) * GHD + 16 * nf + c] =
          (_Float16)(v / (1.f + __expf(-v)));
    }
  }
}

// ---------------------------------------------------------------------------
// gemm2 INTERIOR v15: 8-wave (512-thread) blocks, same per-wave tile
// (32t x 32d). Block covers 64t x 128d; grid 4096. Tests the block-slot
// occupancy hypothesis (resources allow ~6 blocks/CU but measured ~2.2).
// LDS 40.3 KB -> 4 blocks/CU ceiling. (512,2): 256-reg budget, no coercion.
// ---------------------------------------------------------------------------
__global__ __launch_bounds__(512, 2) void gemm2_int(
    const float* __restrict__ x, const _Float16* __restrict__ hlin,
    const _Float16* __restrict__ w2f, const float* __restrict__ b2t,
    float* __restrict__ out) {
  __shared__ float xs[8][35 * 36];
  int t_base = (blockIdx.x >> 4) * 64;
  if ((t_base & 2047) == 0) return;      // boundary tiles: other kernel
  int tid = threadIdx.x;
  int lane = tid & 63, wv = tid >> 6;
  int wr = wv >> 2, wc = wv & 3;
  int g = lane >> 4, c = lane & 15;
  int d_base = (blockIdx.x & 15) * 128;
  float* myxs = xs[wv];

  // stage wave slab: rows t_base+32wr-3 .. +31, cols d_base+32wc .. +32
  {
    int colbase = d_base + 32 * wc;
    int r8 = lane >> 3, c4 = (lane & 7) * 4;
#pragma unroll
    for (int p = 0; p < 5; ++p) {
      int r = p * 8 + r8;
      if (r < 35) {
        int gr = t_base + 32 * wr - 3 + r;
        float4 v = *reinterpret_cast<const float4*>(
            x + (size_t)gr * D_DIM + colbase + c4);
        *reinterpret_cast<float4*>(&myxs[r * 36 + c4]) = v;
      }
    }
  }

  // resident A fragments
  const _Float16* a0p = hlin + (size_t)(t_base + 32 * wr + c) * GHD + 8 * g;
  const _Float16* a1p = hlin + (size_t)(t_base + 32 * wr + 16 + c) * GHD + 8 * g;
  f16x8 A00 = *reinterpret_cast<const f16x8*>(a0p);
  f16x8 A01 = *reinterpret_cast<const f16x8*>(a0p + 32);
  f16x8 A02 = *reinterpret_cast<const f16x8*>(a0p + 64);
  f16x8 A03 = *reinterpret_cast<const f16x8*>(a0p + 96);
  f16x8 A10 = *reinterpret_cast<const f16x8*>(a1p);
  f16x8 A11 = *reinterpret_cast<const f16x8*>(a1p + 32);
  f16x8 A12 = *reinterpret_cast<const f16x8*>(a1p + 64);
  f16x8 A13 = *reinterpret_cast<const f16x8*>(a1p + 96);

  f32x4 oacc[2][2];
#pragma unroll
  for (int m = 0; m < 2; ++m) {
    oacc[m][0] = f32x4{0.f, 0.f, 0.f, 0.f};
    oacc[m][1] = f32x4{0.f, 0.f, 0.f, 0.f};
  }

  int df0 = (d_base >> 4) + 2 * wc;
  const _Float16* wbase = w2f + (size_t)df0 * 4 * 64 * 8 + (size_t)lane * 8;

#pragma unroll
  for (int w = 0; w < 4; ++w) {
    float bw0 = b2t[w * D_DIM + d_base + 32 * wc + c];
    float bw1 = b2t[w * D_DIM + d_base + 32 * wc + 16 + c];
    const _Float16* wp = wbase + (size_t)w * 128 * 4 * 64 * 8;
    f16x8 B00 = *reinterpret_cast<const f16x8*>(wp + 0 * 512);
    f16x8 B01 = *reinterpret_cast<const f16x8*>(wp + 1 * 512);
    f16x8 B02 = *reinterpret_cast<const f16x8*>(wp + 2 * 512);
    f16x8 B03 = *reinterpret_cast<const f16x8*>(wp + 3 * 512);
    f16x8 B10 = *reinterpret_cast<const f16x8*>(wp + 4 * 512);
    f16x8 B11 = *reinterpret_cast<const f16x8*>(wp + 5 * 512);
    f16x8 B12 = *reinterpret_cast<const f16x8*>(wp + 6 * 512);
    f16x8 B13 = *reinterpret_cast<const f16x8*>(wp + 7 * 512);

    f32x4 acc[2][2];
#pragma unroll
    for (int m = 0; m < 2; ++m) {
      acc[m][0] = f32x4{0.f, 0.f, 0.f, 0.f};
      acc[m][1] = f32x4{0.f, 0.f, 0.f, 0.f};
    }
    acc[0][0] = __builtin_amdgcn_mfma_f32_16x16x32_f16(A00, B00, acc[0][0], 0, 0, 0);
    acc[1][0] = __builtin_amdgcn_mfma_f32_16x16x32_f16(A10, B00, acc[1][0], 0, 0, 0);
    acc[0][1] = __builtin_amdgcn_mfma_f32_16x16x32_f16(A00, B10, acc[0][1], 0, 0, 0);
    acc[1][1] = __builtin_amdgcn_mfma_f32_16x16x32_f16(A10, B10, acc[1][1], 0, 0, 0);
    acc[0][0] = __builtin_amdgcn_mfma_f32_16x16x32_f16(A01, B01, acc[0][0], 0, 0, 0);
    acc[1][0] = __builtin_amdgcn_mfma_f32_16x16x32_f16(A11, B01, acc[1][0], 0, 0, 0);
    acc[0][1] = __builtin_amdgcn_mfma_f32_16x16x32_f16(A01, B11, acc[0][1], 0, 0, 0);
    acc[1][1] = __builtin_amdgcn_mfma_f32_16x16x32_f16(A11, B11, acc[1][1], 0, 0, 0);
    acc[0][0] = __builtin_amdgcn_mfma_f32_16x16x32_f16(A02, B02, acc[0][0], 0, 0, 0);
    acc[1][0] = __builtin_amdgcn_mfma_f32_16x16x32_f16(A12, B02, acc[1][0], 0, 0, 0);
    acc[0][1] = __builtin_amdgcn_mfma_f32_16x16x32_f16(A02, B12, acc[0][1], 0, 0, 0);
    acc[1][1] = __builtin_amdgcn_mfma_f32_16x16x32_f16(A12, B12, acc[1][1], 0, 0, 0);
    acc[0][0] = __builtin_amdgcn_mfma_f32_16x16x32_f16(A03, B03, acc[0][0], 0, 0, 0);
    acc[1][0] = __builtin_amdgcn_mfma_f32_16x16x32_f16(A13, B03, acc[1][0], 0, 0, 0);
    acc[0][1] = __builtin_amdgcn_mfma_f32_16x16x32_f16(A03, B13, acc[0][1], 0, 0, 0);
    acc[1][1] = __builtin_amdgcn_mfma_f32_16x16x32_f16(A13, B13, acc[1][1], 0, 0, 0);

    int o = 3 - w;
#pragma unroll
    for (int m = 0; m < 2; ++m)
#pragma unroll
      for (int r = 0; r < 4; ++r) {
        int rl = 16 * m + 4 * g + r;
        float c0 = myxs[(rl + 3 - o) * 36 + c];
        float c1 = myxs[(rl + 3 - o) * 36 + 16 + c];
        oacc[m][0][r] += (acc[m][0][r] + bw0) * c0;
        oacc[m][1][r] += (acc[m][1][r] + bw1) * c1;
      }
  }

#pragma unroll
  for (int m = 0; m < 2; ++m)
#pragma unroll
    for (int r = 0; r < 4; ++r) {
      int t = t_base + 32 * wr + 16 * m + 4 * g + r;
#pragma unroll
      for (int n = 0; n < 2; ++n) {
        int col = d_base + 32 * wc + 16 * n + c;
        float v = oacc[m][n][r];
        out[(size_t)t * D_DIM + col] = v / (1.f + __expf(-v));
      }
    }
}

// ---------------------------------------------------------------------------
// gemm2 BOUNDARY: 256 tiles with t_base = k*2048 (sequence starts).
// Full meta/cache path (unchanged).
// ---------------------------------------------------------------------------
__global__ __launch_bounds__(256) void gemm2_bnd(
    const float* __restrict__ x, const _Float16* __restrict__ hlin,
    const _Float16* __restrict__ w2f, const float* __restrict__ b2t,
    const float* __restrict__ cache, const int* __restrict__ cu_seqlens,
    const int* __restrict__ seq_idx, const int* __restrict__ cache_indices,
    const unsigned char* __restrict__ hi_u8, const int* __restrict__ hi_i32,
    float* __restrict__ out) {
  __shared__ float xs[4][35 * 36];
  int tid = threadIdx.x;
  int lane = tid & 63, wv = tid >> 6;
  int wr = wv >> 1, wc = wv & 1;
  int g = lane >> 4, c = lane & 15;
  int t_base = (blockIdx.x >> 5) * 2048;
  int d_base = (blockIdx.x & 31) * 64;
  float* myxs = xs[wv];

  {
    int colbase = d_base + 32 * wc;
    int r8 = lane >> 3, c4 = (lane & 7) * 4;
#pragma unroll
    for (int p = 0; p < 5; ++p) {
      int r = p * 8 + r8;
      if (r < 35) {
        int gr = t_base + 32 * wr - 3 + r;
        gr = max(0, gr);
        float4 v = *reinterpret_cast<const float4*>(
            x + (size_t)gr * D_DIM + colbase + c4);
        *reinterpret_cast<float4*>(&myxs[r * 36 + c4]) = v;
      }
    }
  }

  float b2v[4][2];
#pragma unroll
  for (int w = 0; w < 4; ++w)
#pragma unroll
    for (int n = 0; n < 2; ++n)
      b2v[w][n] = b2t[w * D_DIM + d_base + 32 * wc + 16 * n + c];

  const _Float16* a0p = hlin + (size_t)(t_base + 32 * wr + c) * GHD + 8 * g;
  const _Float16* a1p = hlin + (size_t)(t_base + 32 * wr + 16 + c) * GHD + 8 * g;
  f16x8 A00 = *reinterpret_cast<const f16x8*>(a0p);
  f16x8 A01 = *reinterpret_cast<const f16x8*>(a0p + 32);
  f16x8 A02 = *reinterpret_cast<const f16x8*>(a0p + 64);
  f16x8 A03 = *reinterpret_cast<const f16x8*>(a0p + 96);
  f16x8 A10 = *reinterpret_cast<const f16x8*>(a1p);
  f16x8 A11 = *reinterpret_cast<const f16x8*>(a1p + 32);
  f16x8 A12 = *reinterpret_cast<const f16x8*>(a1p + 64);
  f16x8 A13 = *reinterpret_cast<const f16x8*>(a1p + 96);

  int meta[8];
#pragma unroll
  for (int m = 0; m < 2; ++m)
#pragma unroll
    for (int r = 0; r < 4; ++r) {
      int t = t_base + 32 * wr + 16 * m + 4 * g + r;
      int s = seq_idx[t];
      int pos = t - cu_seqlens[s];
      int ci = cache_indices[s];
      int hi = (hi_u8[s] != 0) | (hi_i32[s] != 0);
      meta[m * 4 + r] = pos | (ci << 16) | (hi << 24);
    }

  f32x4 oacc[2][2];
#pragma unroll
  for (int m = 0; m < 2; ++m) {
    oacc[m][0] = f32x4{0.f, 0.f, 0.f, 0.f};
    oacc[m][1] = f32x4{0.f, 0.f, 0.f, 0.f};
  }

  int df0 = (d_base >> 4) + 2 * wc;

#pragma unroll
  for (int w = 0; w < 4; ++w) {
    f32x4 acc[2][2];
#pragma unroll
    for (int m = 0; m < 2; ++m) {
      acc[m][0] = f32x4{0.f, 0.f, 0.f, 0.f};
      acc[m][1] = f32x4{0.f, 0.f, 0.f, 0.f};
    }
#pragma unroll
    for (int kk = 0; kk < 4; ++kk) {
      f16x8 B0 = *reinterpret_cast<const f16x8*>(
          w2f + ((size_t)((w * 128 + df0) * 4 + kk) * 64 + lane) * 8);
      f16x8 B1 = *reinterpret_cast<const f16x8*>(
          w2f + ((size_t)((w * 128 + df0 + 1) * 4 + kk) * 64 + lane) * 8);
      f16x8 Am0 = (kk == 0) ? A00 : (kk == 1) ? A01 : (kk == 2) ? A02 : A03;
      f16x8 Am1 = (kk == 0) ? A10 : (kk == 1) ? A11 : (kk == 2) ? A12 : A13;
      acc[0][0] = __builtin_amdgcn_mfma_f32_16x16x32_f16(Am0, B0, acc[0][0], 0, 0, 0);
      acc[0][1] = __builtin_amdgcn_mfma_f32_16x16x32_f16(Am0, B1, acc[0][1], 0, 0, 0);
      acc[1][0] = __builtin_amdgcn_mfma_f32_16x16x32_f16(Am1, B0, acc[1][0], 0, 0, 0);
      acc[1][1] = __builtin_amdgcn_mfma_f32_16x16x32_f16(Am1, B1, acc[1][1], 0, 0, 0);
    }
    int o = 3 - w;
#pragma unroll
    for (int m = 0; m < 2; ++m)
#pragma unroll
      for (int r = 0; r < 4; ++r) {
        int mt = meta[m * 4 + r];
        int pos = mt & 0xffff;
        int rl = 16 * m + 4 * g + r;
#pragma unroll
        for (int n = 0; n < 2; ++n) {
          int col = 32 * wc + 16 * n + c;
          float ctx;
          if (pos >= o) {
            ctx = myxs[(rl + 3 - o) * 36 + 16 * n + c];
          } else if ((mt >> 24) & 1) {
            int ci = (mt >> 16) & 0xff;
            ctx = cache[(size_t)ci * (D_DIM * W_DIM) +
                        (size_t)(d_base + col) * W_DIM + (4 + pos - o)];
          } else {
            ctx = 0.f;
          }
          oacc[m][n][r] += (acc[m][n][r] + b2v[w][n]) * ctx;
        }
      }
  }

#pragma unroll
  for (int m = 0; m < 2; ++m)
#pragma unroll
    for (int r = 0; r < 4; ++r) {
      int t = t_base + 32 * wr + 16 * m + 4 * g + r;
#pragma unroll
      for (int n = 0; n < 2; ++n) {
        int col = d_base + 32 * wc + 16 * n + c;
        float v = oacc[m][n][r];
        out[(size_t)t * D_DIM + col] = v / (1.f + __expf(-v));
      }
    }
}

// ---------------------------------------------------------------------------
// cache update (unchanged)
// ---------------------------------------------------------------------------
__global__ __launch_bounds__(256) void cache_kernel(
    const float* __restrict__ x, const float* __restrict__ cache,
    const int* __restrict__ cu, const int* __restrict__ ci_arr,
    const unsigned char* __restrict__ hi_u8, const int* __restrict__ hi_i32,
    float* __restrict__ outc) {
  int idx = blockIdx.x * 256 + threadIdx.x;
  if (idx >= B_DIM * D_DIM * W_DIM) return;
  int b = idx >> 13, d = (idx >> 2) & 2047, j = idx & 3;
  float val = cache[idx];
  if (j >= 1) {
    for (int i = 0; i < B_DIM; ++i) {   // last-wins scatter semantics
      if (ci_arr[i] == b) {
        int L = cu[i + 1] - cu[i];
        int rel = L - (W_DIM - 1) + (j - 1);
        if (rel >= 0) {
          int tok = cu[i] + rel;
          tok = max(0, min(T_DIM - 1, tok));
          val = x[(size_t)tok * D_DIM + d];
        } else {
          bool hi = (hi_u8[i] != 0) | (hi_i32[i] != 0);
          int slot = 4 + rel;
          slot = max(0, min(3, slot));
          val = hi ? cache[b * (D_DIM * W_DIM) + d * 4 + slot]
                   : cache[b * (D_DIM * W_DIM) + d * 4 + j];
        }
      }
    }
  }
  outc[idx] = val;
}

extern "C" void kernel_launch(void* const* d_in, const int* in_sizes, int n_in,
                              void* d_out, int out_size, void* d_ws, size_t ws_size,
                              hipStream_t stream) {
  const float* x     = (const float*)d_in[0];
  const float* gen   = (const float*)d_in[1];
  const float* w1    = (const float*)d_in[2];
  const float* w2    = (const float*)d_in[3];
  const float* b2    = (const float*)d_in[4];
  const float* cache = (const float*)d_in[5];
  const int* cu      = (const int*)d_in[6];
  const int* seq     = (const int*)d_in[7];
  const int* cidx    = (const int*)d_in[8];
  const unsigned char* hi8 = (const unsigned char*)d_in[9];
  const int* hi32          = (const int*)d_in[9];
  float* out = (float*)d_out;

  char* ws = (char*)d_ws;
  _Float16* w1f  = (_Float16*)(ws + WS_W1F);
  _Float16* w2f  = (_Float16*)(ws + WS_W2F);
  float*    b2t  = (float*)(ws + WS_B2T);
  _Float16* hlin = (_Float16*)(ws + WS_HLIN);

  prep_kernel<<<dim3(584), dim3(256), 0, stream>>>(w1, w2, b2, w1f, w2f, b2t);
  gemm1_kernel<<<dim3(1024), dim3(256), 0, stream>>>(gen, w1f, hlin);
  gemm2_int<<<dim3(4096), dim3(512), 0, stream>>>(x, hlin, w2f, b2t, out);
  gemm2_bnd<<<dim3(256), dim3(256), 0, stream>>>(
      x, hlin, w2f, b2t, cache, cu, seq, cidx, hi8, hi32, out);
  cache_kernel<<<dim3(256), dim3(256), 0, stream>>>(
      x, cache, cu, cidx, hi8, hi32, out + (size_t)T_DIM * D_DIM);
}

// Round 20
// 174.562 us; speedup vs baseline: 1.0199x; 1.0199x over previous
//
#include <hip/hip_runtime.h>

#define T_DIM 16384
#define D_DIM 2048
#define GHD   128
#define W_DIM 4
#define B_DIM 8

typedef _Float16 f16x8 __attribute__((ext_vector_type(8)));
typedef float    f32x4 __attribute__((ext_vector_type(4)));

__device__ __forceinline__ float silu_f(float v) {
  // v * rcp(1+exp(-v)): rcp approx (~2^-22 rel err) vs ~10-instr exact divide
  return v * __builtin_amdgcn_rcpf(1.f + __expf(-v));
}

// workspace layout (bytes)
#define WS_W1F  0
#define WS_W2F  (512*1024)
#define WS_B2T  (WS_W2F + 2*1024*1024)
#define WS_HLIN (WS_B2T + 32*1024)

// ---------------------------------------------------------------------------
// prep: coalesced via LDS-staged transpose.
// ---------------------------------------------------------------------------
__global__ __launch_bounds__(256) void prep_kernel(
    const float* __restrict__ w1, const float* __restrict__ w2,
    const float* __restrict__ b2, _Float16* __restrict__ w1f,
    _Float16* __restrict__ w2f, float* __restrict__ b2t) {
  __shared__ float sm[4096];
  int bid = blockIdx.x, tid = threadIdx.x;
  int lane = tid & 63;
  int g = lane >> 4, c = lane & 15;

  if (bid < 512) {                       // ---- W2F ----
    int df = bid >> 2, kk = bid & 3;
#pragma unroll
    for (int q = 0; q < 8; ++q) {
      int li = q * 256 + tid;
      int kl = li >> 6, nl = li & 63;
      sm[li] = w2[(size_t)(32 * kk + kl) * (D_DIM * W_DIM) + 64 * df + nl];
    }
    __syncthreads();
    int w = tid >> 6;
    f16x8 v;
#pragma unroll
    for (int i = 0; i < 8; ++i)
      v[i] = (_Float16)sm[(8 * g + i) * 64 + 4 * c + w];
    int fid = (w * 128 + df) * 4 + kk;
    *reinterpret_cast<f16x8*>(w2f + ((size_t)fid * 64 + lane) * 8) = v;
  } else if (bid < 576) {                // ---- W1F ----
    int kk = bid - 512;
#pragma unroll
    for (int q = 0; q < 16; ++q) {
      int li = q * 256 + tid;
      int kl = li >> 7, nl = li & 127;
      sm[li] = w1[(32 * kk + kl) * GHD + nl];
    }
    __syncthreads();
#pragma unroll
    for (int h = 0; h < 2; ++h) {
      int nf = (tid >> 6) * 2 + h;
      f16x8 v;
#pragma unroll
      for (int i = 0; i < 8; ++i)
        v[i] = (_Float16)sm[(8 * g + i) * GHD + 16 * nf + c];
      *reinterpret_cast<f16x8*>(w1f + ((size_t)(kk * 8 + nf) * 64 + lane) * 8) = v;
    }
  } else {                               // ---- B2T ----
#pragma unroll
    for (int q = 0; q < 4; ++q) {
      int e = (bid - 576) * 1024 + q * 256 + tid;
      int w = e >> 11, d = e & 2047;
      b2t[w * D_DIM + d] = b2[d * 4 + w];
    }
  }
}

// ---------------------------------------------------------------------------
// gemm1 v2 (measured win): k-split across waves; gen loaded once per block;
// LDS reduce red[nf][wv][lane].
// ---------------------------------------------------------------------------
__global__ __launch_bounds__(256) void gemm1_kernel(
    const float* __restrict__ gen, const _Float16* __restrict__ w1f,
    _Float16* __restrict__ hlin) {
  __shared__ f32x4 red[8][4][64];
  int tid = threadIdx.x;
  int lane = tid & 63, wv = tid >> 6;
  int g = lane >> 4, c = lane & 15;
  int row = blockIdx.x * 16 + c;
  const float* arow = gen + (size_t)row * D_DIM;

  f32x4 acc[8];
#pragma unroll
  for (int nf = 0; nf < 8; ++nf) acc[nf] = f32x4{0.f, 0.f, 0.f, 0.f};

  for (int it = 0; it < 16; ++it) {
    int kk = 16 * wv + it;
    float4 a0 = *reinterpret_cast<const float4*>(arow + kk * 32 + 8 * g);
    float4 a1 = *reinterpret_cast<const float4*>(arow + kk * 32 + 8 * g + 4);
    f16x8 af;
    af[0] = (_Float16)a0.x; af[1] = (_Float16)a0.y;
    af[2] = (_Float16)a0.z; af[3] = (_Float16)a0.w;
    af[4] = (_Float16)a1.x; af[5] = (_Float16)a1.y;
    af[6] = (_Float16)a1.z; af[7] = (_Float16)a1.w;
#pragma unroll
    for (int nf = 0; nf < 8; ++nf) {
      f16x8 b = *reinterpret_cast<const f16x8*>(
          w1f + ((size_t)(kk * 8 + nf) * 64 + lane) * 8);
      acc[nf] = __builtin_amdgcn_mfma_f32_16x16x32_f16(af, b, acc[nf], 0, 0, 0);
    }
  }

#pragma unroll
  for (int nf = 0; nf < 8; ++nf) red[nf][wv][lane] = acc[nf];
  __syncthreads();

  int trow = blockIdx.x * 16 + 4 * g;
#pragma unroll
  for (int h = 0; h < 2; ++h) {
    int nf = 2 * wv + h;
    f32x4 s0 = red[nf][0][lane];
    f32x4 s1 = red[nf][1][lane];
    f32x4 s2 = red[nf][2][lane];
    f32x4 s3 = red[nf][3][lane];
    f32x4 s;
#pragma unroll
    for (int r = 0; r < 4; ++r) s[r] = (s0[r] + s1[r]) + (s2[r] + s3[r]);
#pragma unroll
    for (int r = 0; r < 4; ++r)
      hlin[(size_t)(trow + r) * GHD + 16 * nf + c] = (_Float16)silu_f(s[r]);
  }
}

// ---------------------------------------------------------------------------
// gemm2 INTERIOR v11 (measured best 117us): t-major decode, batched B hoist,
// (256,3). Wave 32t x 32d; boundary tiles skipped (bnd kernel owns them).
// ---------------------------------------------------------------------------
__global__ __launch_bounds__(256, 3) void gemm2_int(
    const float* __restrict__ x, const _Float16* __restrict__ hlin,
    const _Float16* __restrict__ w2f, const float* __restrict__ b2t,
    float* __restrict__ out) {
  __shared__ float xs[4][35 * 36];
  int t_base = (blockIdx.x >> 5) * 64;
  if ((t_base & 2047) == 0) return;      // boundary tiles: other kernel
  int tid = threadIdx.x;
  int lane = tid & 63, wv = tid >> 6;
  int wr = wv >> 1, wc = wv & 1;
  int g = lane >> 4, c = lane & 15;
  int d_base = (blockIdx.x & 31) * 64;
  float* myxs = xs[wv];

  // stage wave slab: rows t_base+32wr-3 .. +31, cols d_base+32wc .. +32
  {
    int colbase = d_base + 32 * wc;
    int r8 = lane >> 3, c4 = (lane & 7) * 4;
#pragma unroll
    for (int p = 0; p < 5; ++p) {
      int r = p * 8 + r8;
      if (r < 35) {
        int gr = t_base + 32 * wr - 3 + r;
        float4 v = *reinterpret_cast<const float4*>(
            x + (size_t)gr * D_DIM + colbase + c4);
        *reinterpret_cast<float4*>(&myxs[r * 36 + c4]) = v;
      }
    }
  }

  // resident A fragments
  const _Float16* a0p = hlin + (size_t)(t_base + 32 * wr + c) * GHD + 8 * g;
  const _Float16* a1p = hlin + (size_t)(t_base + 32 * wr + 16 + c) * GHD + 8 * g;
  f16x8 A00 = *reinterpret_cast<const f16x8*>(a0p);
  f16x8 A01 = *reinterpret_cast<const f16x8*>(a0p + 32);
  f16x8 A02 = *reinterpret_cast<const f16x8*>(a0p + 64);
  f16x8 A03 = *reinterpret_cast<const f16x8*>(a0p + 96);
  f16x8 A10 = *reinterpret_cast<const f16x8*>(a1p);
  f16x8 A11 = *reinterpret_cast<const f16x8*>(a1p + 32);
  f16x8 A12 = *reinterpret_cast<const f16x8*>(a1p + 64);
  f16x8 A13 = *reinterpret_cast<const f16x8*>(a1p + 96);

  f32x4 oacc[2][2];
#pragma unroll
  for (int m = 0; m < 2; ++m) {
    oacc[m][0] = f32x4{0.f, 0.f, 0.f, 0.f};
    oacc[m][1] = f32x4{0.f, 0.f, 0.f, 0.f};
  }

  int df0 = (d_base >> 4) + 2 * wc;
  const _Float16* wbase = w2f + (size_t)df0 * 4 * 64 * 8 + (size_t)lane * 8;

#pragma unroll
  for (int w = 0; w < 4; ++w) {
    float bw0 = b2t[w * D_DIM + d_base + 32 * wc + c];
    float bw1 = b2t[w * D_DIM + d_base + 32 * wc + 16 + c];
    const _Float16* wp = wbase + (size_t)w * 128 * 4 * 64 * 8;
    f16x8 B00 = *reinterpret_cast<const f16x8*>(wp + 0 * 512);
    f16x8 B01 = *reinterpret_cast<const f16x8*>(wp + 1 * 512);
    f16x8 B02 = *reinterpret_cast<const f16x8*>(wp + 2 * 512);
    f16x8 B03 = *reinterpret_cast<const f16x8*>(wp + 3 * 512);
    f16x8 B10 = *reinterpret_cast<const f16x8*>(wp + 4 * 512);
    f16x8 B11 = *reinterpret_cast<const f16x8*>(wp + 5 * 512);
    f16x8 B12 = *reinterpret_cast<const f16x8*>(wp + 6 * 512);
    f16x8 B13 = *reinterpret_cast<const f16x8*>(wp + 7 * 512);

    f32x4 acc[2][2];
#pragma unroll
    for (int m = 0; m < 2; ++m) {
      acc[m][0] = f32x4{0.f, 0.f, 0.f, 0.f};
      acc[m][1] = f32x4{0.f, 0.f, 0.f, 0.f};
    }
    acc[0][0] = __builtin_amdgcn_mfma_f32_16x16x32_f16(A00, B00, acc[0][0], 0, 0, 0);
    acc[1][0] = __builtin_amdgcn_mfma_f32_16x16x32_f16(A10, B00, acc[1][0], 0, 0, 0);
    acc[0][1] = __builtin_amdgcn_mfma_f32_16x16x32_f16(A00, B10, acc[0][1], 0, 0, 0);
    acc[1][1] = __builtin_amdgcn_mfma_f32_16x16x32_f16(A10, B10, acc[1][1], 0, 0, 0);
    acc[0][0] = __builtin_amdgcn_mfma_f32_16x16x32_f16(A01, B01, acc[0][0], 0, 0, 0);
    acc[1][0] = __builtin_amdgcn_mfma_f32_16x16x32_f16(A11, B01, acc[1][0], 0, 0, 0);
    acc[0][1] = __builtin_amdgcn_mfma_f32_16x16x32_f16(A01, B11, acc[0][1], 0, 0, 0);
    acc[1][1] = __builtin_amdgcn_mfma_f32_16x16x32_f16(A11, B11, acc[1][1], 0, 0, 0);
    acc[0][0] = __builtin_amdgcn_mfma_f32_16x16x32_f16(A02, B02, acc[0][0], 0, 0, 0);
    acc[1][0] = __builtin_amdgcn_mfma_f32_16x16x32_f16(A12, B02, acc[1][0], 0, 0, 0);
    acc[0][1] = __builtin_amdgcn_mfma_f32_16x16x32_f16(A02, B12, acc[0][1], 0, 0, 0);
    acc[1][1] = __builtin_amdgcn_mfma_f32_16x16x32_f16(A12, B12, acc[1][1], 0, 0, 0);
    acc[0][0] = __builtin_amdgcn_mfma_f32_16x16x32_f16(A03, B03, acc[0][0], 0, 0, 0);
    acc[1][0] = __builtin_amdgcn_mfma_f32_16x16x32_f16(A13, B03, acc[1][0], 0, 0, 0);
    acc[0][1] = __builtin_amdgcn_mfma_f32_16x16x32_f16(A03, B13, acc[0][1], 0, 0, 0);
    acc[1][1] = __builtin_amdgcn_mfma_f32_16x16x32_f16(A13, B13, acc[1][1], 0, 0, 0);

    int o = 3 - w;
#pragma unroll
    for (int m = 0; m < 2; ++m)
#pragma unroll
      for (int r = 0; r < 4; ++r) {
        int rl = 16 * m + 4 * g + r;
        float c0 = myxs[(rl + 3 - o) * 36 + c];
        float c1 = myxs[(rl + 3 - o) * 36 + 16 + c];
        oacc[m][0][r] += (acc[m][0][r] + bw0) * c0;
        oacc[m][1][r] += (acc[m][1][r] + bw1) * c1;
      }
  }

#pragma unroll
  for (int m = 0; m < 2; ++m)
#pragma unroll
    for (int r = 0; r < 4; ++r) {
      int t = t_base + 32 * wr + 16 * m + 4 * g + r;
#pragma unroll
      for (int n = 0; n < 2; ++n) {
        int col = d_base + 32 * wc + 16 * n + c;
        out[(size_t)t * D_DIM + col] = silu_f(oacc[m][n][r]);
      }
    }
}

// ---------------------------------------------------------------------------
// gemm2 BOUNDARY: 256 tiles with t_base = k*2048 (sequence starts).
// Full meta/cache path.
// ---------------------------------------------------------------------------
__global__ __launch_bounds__(256) void gemm2_bnd(
    const float* __restrict__ x, const _Float16* __restrict__ hlin,
    const _Float16* __restrict__ w2f, const float* __restrict__ b2t,
    const float* __restrict__ cache, const int* __restrict__ cu_seqlens,
    const int* __restrict__ seq_idx, const int* __restrict__ cache_indices,
    const unsigned char* __restrict__ hi_u8, const int* __restrict__ hi_i32,
    float* __restrict__ out) {
  __shared__ float xs[4][35 * 36];
  int tid = threadIdx.x;
  int lane = tid & 63, wv = tid >> 6;
  int wr = wv >> 1, wc = wv & 1;
  int g = lane >> 4, c = lane & 15;
  int t_base = (blockIdx.x >> 5) * 2048;
  int d_base = (blockIdx.x & 31) * 64;
  float* myxs = xs[wv];

  {
    int colbase = d_base + 32 * wc;
    int r8 = lane >> 3, c4 = (lane & 7) * 4;
#pragma unroll
    for (int p = 0; p < 5; ++p) {
      int r = p * 8 + r8;
      if (r < 35) {
        int gr = t_base + 32 * wr - 3 + r;
        gr = max(0, gr);
        float4 v = *reinterpret_cast<const float4*>(
            x + (size_t)gr * D_DIM + colbase + c4);
        *reinterpret_cast<float4*>(&myxs[r * 36 + c4]) = v;
      }
    }
  }

  float b2v[4][2];
#pragma unroll
  for (int w = 0; w < 4; ++w)
#pragma unroll
    for (int n = 0; n < 2; ++n)
      b2v[w][n] = b2t[w * D_DIM + d_base + 32 * wc + 16 * n + c];

  const _Float16* a0p = hlin + (size_t)(t_base + 32 * wr + c) * GHD + 8 * g;
  const _Float16* a1p = hlin + (size_t)(t_base + 32 * wr + 16 + c) * GHD + 8 * g;
  f16x8 A00 = *reinterpret_cast<const f16x8*>(a0p);
  f16x8 A01 = *reinterpret_cast<const f16x8*>(a0p + 32);
  f16x8 A02 = *reinterpret_cast<const f16x8*>(a0p + 64);
  f16x8 A03 = *reinterpret_cast<const f16x8*>(a0p + 96);
  f16x8 A10 = *reinterpret_cast<const f16x8*>(a1p);
  f16x8 A11 = *reinterpret_cast<const f16x8*>(a1p + 32);
  f16x8 A12 = *reinterpret_cast<const f16x8*>(a1p + 64);
  f16x8 A13 = *reinterpret_cast<const f16x8*>(a1p + 96);

  int meta[8];
#pragma unroll
  for (int m = 0; m < 2; ++m)
#pragma unroll
    for (int r = 0; r < 4; ++r) {
      int t = t_base + 32 * wr + 16 * m + 4 * g + r;
      int s = seq_idx[t];
      int pos = t - cu_seqlens[s];
      int ci = cache_indices[s];
      int hi = (hi_u8[s] != 0) | (hi_i32[s] != 0);
      meta[m * 4 + r] = pos | (ci << 16) | (hi << 24);
    }

  f32x4 oacc[2][2];
#pragma unroll
  for (int m = 0; m < 2; ++m) {
    oacc[m][0] = f32x4{0.f, 0.f, 0.f, 0.f};
    oacc[m][1] = f32x4{0.f, 0.f, 0.f, 0.f};
  }

  int df0 = (d_base >> 4) + 2 * wc;

#pragma unroll
  for (int w = 0; w < 4; ++w) {
    f32x4 acc[2][2];
#pragma unroll
    for (int m = 0; m < 2; ++m) {
      acc[m][0] = f32x4{0.f, 0.f, 0.f, 0.f};
      acc[m][1] = f32x4{0.f, 0.f, 0.f, 0.f};
    }
#pragma unroll
    for (int kk = 0; kk < 4; ++kk) {
      f16x8 B0 = *reinterpret_cast<const f16x8*>(
          w2f + ((size_t)((w * 128 + df0) * 4 + kk) * 64 + lane) * 8);
      f16x8 B1 = *reinterpret_cast<const f16x8*>(
          w2f + ((size_t)((w * 128 + df0 + 1) * 4 + kk) * 64 + lane) * 8);
      f16x8 Am0 = (kk == 0) ? A00 : (kk == 1) ? A01 : (kk == 2) ? A02 : A03;
      f16x8 Am1 = (kk == 0) ? A10 : (kk == 1) ? A11 : (kk == 2) ? A12 : A13;
      acc[0][0] = __builtin_amdgcn_mfma_f32_16x16x32_f16(Am0, B0, acc[0][0], 0, 0, 0);
      acc[0][1] = __builtin_amdgcn_mfma_f32_16x16x32_f16(Am0, B1, acc[0][1], 0, 0, 0);
      acc[1][0] = __builtin_amdgcn_mfma_f32_16x16x32_f16(Am1, B0, acc[1][0], 0, 0, 0);
      acc[1][1] = __builtin_amdgcn_mfma_f32_16x16x32_f16(Am1, B1, acc[1][1], 0, 0, 0);
    }
    int o = 3 - w;
#pragma unroll
    for (int m = 0; m < 2; ++m)
#pragma unroll
      for (int r = 0; r < 4; ++r) {
        int mt = meta[m * 4 + r];
        int pos = mt & 0xffff;
        int rl = 16 * m + 4 * g + r;
#pragma unroll
        for (int n = 0; n < 2; ++n) {
          int col = 32 * wc + 16 * n + c;
          float ctx;
          if (pos >= o) {
            ctx = myxs[(rl + 3 - o) * 36 + 16 * n + c];
          } else if ((mt >> 24) & 1) {
            int ci = (mt >> 16) & 0xff;
            ctx = cache[(size_t)ci * (D_DIM * W_DIM) +
                        (size_t)(d_base + col) * W_DIM + (4 + pos - o)];
          } else {
            ctx = 0.f;
          }
          oacc[m][n][r] += (acc[m][n][r] + b2v[w][n]) * ctx;
        }
      }
  }

#pragma unroll
  for (int m = 0; m < 2; ++m)
#pragma unroll
    for (int r = 0; r < 4; ++r) {
      int t = t_base + 32 * wr + 16 * m + 4 * g + r;
#pragma unroll
      for (int n = 0; n < 2; ++n) {
        int col = d_base + 32 * wc + 16 * n + c;
        out[(size_t)t * D_DIM + col] = silu_f(oacc[m][n][r]);
      }
    }
}

// ---------------------------------------------------------------------------
// cache update (unchanged)
// ---------------------------------------------------------------------------
__global__ __launch_bounds__(256) void cache_kernel(
    const float* __restrict__ x, const float* __restrict__ cache,
    const int* __restrict__ cu, const int* __restrict__ ci_arr,
    const unsigned char* __restrict__ hi_u8, const int* __restrict__ hi_i32,
    float* __restrict__ outc) {
  int idx = blockIdx.x * 256 + threadIdx.x;
  if (idx >= B_DIM * D_DIM * W_DIM) return;
  int b = idx >> 13, d = (idx >> 2) & 2047, j = idx & 3;
  float val = cache[idx];
  if (j >= 1) {
    for (int i = 0; i < B_DIM; ++i) {   // last-wins scatter semantics
      if (ci_arr[i] == b) {
        int L = cu[i + 1] - cu[i];
        int rel = L - (W_DIM - 1) + (j - 1);
        if (rel >= 0) {
          int tok = cu[i] + rel;
          tok = max(0, min(T_DIM - 1, tok));
          val = x[(size_t)tok * D_DIM + d];
        } else {
          bool hi = (hi_u8[i] != 0) | (hi_i32[i] != 0);
          int slot = 4 + rel;
          slot = max(0, min(3, slot));
          val = hi ? cache[b * (D_DIM * W_DIM) + d * 4 + slot]
                   : cache[b * (D_DIM * W_DIM) + d * 4 + j];
        }
      }
    }
  }
  outc[idx] = val;
}

extern "C" void kernel_launch(void* const* d_in, const int* in_sizes, int n_in,
                              void* d_out, int out_size, void* d_ws, size_t ws_size,
                              hipStream_t stream) {
  const float* x     = (const float*)d_in[0];
  const float* gen   = (const float*)d_in[1];
  const float* w1    = (const float*)d_in[2];
  const float* w2    = (const float*)d_in[3];
  const float* b2    = (const float*)d_in[4];
  const float* cache = (const float*)d_in[5];
  const int* cu      = (const int*)d_in[6];
  const int* seq     = (const int*)d_in[7];
  const int* cidx    = (const int*)d_in[8];
  const unsigned char* hi8 = (const unsigned char*)d_in[9];
  const int* hi32          = (const int*)d_in[9];
  float* out = (float*)d_out;

  char* ws = (char*)d_ws;
  _Float16* w1f  = (_Float16*)(ws + WS_W1F);
  _Float16* w2f  = (_Float16*)(ws + WS_W2F);
  float*    b2t  = (float*)(ws + WS_B2T);
  _Float16* hlin = (_Float16*)(ws + WS_HLIN);

  prep_kernel<<<dim3(584), dim3(256), 0, stream>>>(w1, w2, b2, w1f, w2f, b2t);
  gemm1_kernel<<<dim3(1024), dim3(256), 0, stream>>>(gen, w1f, hlin);
  gemm2_int<<<dim3(8192), dim3(256), 0, stream>>>(x, hlin, w2f, b2t, out);
  gemm2_bnd<<<dim3(256), dim3(256), 0, stream>>>(
      x, hlin, w2f, b2t, cache, cu, seq, cidx, hi8, hi32, out);
  cache_kernel<<<dim3(256), dim3(256), 0, stream>>>(
      x, cache, cu, cidx, hi8, hi32, out + (size_t)T_DIM * D_DIM);
}

// Round 21
// 166.047 us; speedup vs baseline: 1.0722x; 1.0513x over previous
//
#include <hip/hip_runtime.h>

#define T_DIM 16384
#define D_DIM 2048
#define GHD   128
#define W_DIM 4
#define B_DIM 8

typedef _Float16 f16x8 __attribute__((ext_vector_type(8)));
typedef float    f32x4 __attribute__((ext_vector_type(4)));

__device__ __forceinline__ float silu_f(float v) {
  return v * __builtin_amdgcn_rcpf(1.f + __expf(-v));
}

// workspace layout (bytes)
#define WS_W1F  0
#define WS_W2F  (512*1024)
#define WS_B2T  (WS_W2F + 2*1024*1024)
#define WS_HLIN (WS_B2T + 32*1024)

// ---------------------------------------------------------------------------
// prep: coalesced via LDS-staged transpose.
// ---------------------------------------------------------------------------
__global__ __launch_bounds__(256) void prep_kernel(
    const float* __restrict__ w1, const float* __restrict__ w2,
    const float* __restrict__ b2, _Float16* __restrict__ w1f,
    _Float16* __restrict__ w2f, float* __restrict__ b2t) {
  __shared__ float sm[4096];
  int bid = blockIdx.x, tid = threadIdx.x;
  int lane = tid & 63;
  int g = lane >> 4, c = lane & 15;

  if (bid < 512) {                       // ---- W2F ----
    int df = bid >> 2, kk = bid & 3;
#pragma unroll
    for (int q = 0; q < 8; ++q) {
      int li = q * 256 + tid;
      int kl = li >> 6, nl = li & 63;
      sm[li] = w2[(size_t)(32 * kk + kl) * (D_DIM * W_DIM) + 64 * df + nl];
    }
    __syncthreads();
    int w = tid >> 6;
    f16x8 v;
#pragma unroll
    for (int i = 0; i < 8; ++i)
      v[i] = (_Float16)sm[(8 * g + i) * 64 + 4 * c + w];
    int fid = (w * 128 + df) * 4 + kk;
    *reinterpret_cast<f16x8*>(w2f + ((size_t)fid * 64 + lane) * 8) = v;
  } else if (bid < 576) {                // ---- W1F ----
    int kk = bid - 512;
#pragma unroll
    for (int q = 0; q < 16; ++q) {
      int li = q * 256 + tid;
      int kl = li >> 7, nl = li & 127;
      sm[li] = w1[(32 * kk + kl) * GHD + nl];
    }
    __syncthreads();
#pragma unroll
    for (int h = 0; h < 2; ++h) {
      int nf = (tid >> 6) * 2 + h;
      f16x8 v;
#pragma unroll
      for (int i = 0; i < 8; ++i)
        v[i] = (_Float16)sm[(8 * g + i) * GHD + 16 * nf + c];
      *reinterpret_cast<f16x8*>(w1f + ((size_t)(kk * 8 + nf) * 64 + lane) * 8) = v;
    }
  } else {                               // ---- B2T ----
#pragma unroll
    for (int q = 0; q < 4; ++q) {
      int e = (bid - 576) * 1024 + q * 256 + tid;
      int w = e >> 11, d = e & 2047;
      b2t[w * D_DIM + d] = b2[d * 4 + w];
    }
  }
}

// ---------------------------------------------------------------------------
// gemm1 v2: k-split across waves; gen loaded once per block; LDS reduce.
// ---------------------------------------------------------------------------
__global__ __launch_bounds__(256) void gemm1_kernel(
    const float* __restrict__ gen, const _Float16* __restrict__ w1f,
    _Float16* __restrict__ hlin) {
  __shared__ f32x4 red[8][4][64];
  int tid = threadIdx.x;
  int lane = tid & 63, wv = tid >> 6;
  int g = lane >> 4, c = lane & 15;
  int row = blockIdx.x * 16 + c;
  const float* arow = gen + (size_t)row * D_DIM;

  f32x4 acc[8];
#pragma unroll
  for (int nf = 0; nf < 8; ++nf) acc[nf] = f32x4{0.f, 0.f, 0.f, 0.f};

  for (int it = 0; it < 16; ++it) {
    int kk = 16 * wv + it;
    float4 a0 = *reinterpret_cast<const float4*>(arow + kk * 32 + 8 * g);
    float4 a1 = *reinterpret_cast<const float4*>(arow + kk * 32 + 8 * g + 4);
    f16x8 af;
    af[0] = (_Float16)a0.x; af[1] = (_Float16)a0.y;
    af[2] = (_Float16)a0.z; af[3] = (_Float16)a0.w;
    af[4] = (_Float16)a1.x; af[5] = (_Float16)a1.y;
    af[6] = (_Float16)a1.z; af[7] = (_Float16)a1.w;
#pragma unroll
    for (int nf = 0; nf < 8; ++nf) {
      f16x8 b = *reinterpret_cast<const f16x8*>(
          w1f + ((size_t)(kk * 8 + nf) * 64 + lane) * 8);
      acc[nf] = __builtin_amdgcn_mfma_f32_16x16x32_f16(af, b, acc[nf], 0, 0, 0);
    }
  }

#pragma unroll
  for (int nf = 0; nf < 8; ++nf) red[nf][wv][lane] = acc[nf];
  __syncthreads();

  int trow = blockIdx.x * 16 + 4 * g;
#pragma unroll
  for (int h = 0; h < 2; ++h) {
    int nf = 2 * wv + h;
    f32x4 s0 = red[nf][0][lane];
    f32x4 s1 = red[nf][1][lane];
    f32x4 s2 = red[nf][2][lane];
    f32x4 s3 = red[nf][3][lane];
    f32x4 s;
#pragma unroll
    for (int r = 0; r < 4; ++r) s[r] = (s0[r] + s1[r]) + (s2[r] + s3[r]);
#pragma unroll
    for (int r = 0; r < 4; ++r)
      hlin[(size_t)(trow + r) * GHD + 16 * nf + c] = (_Float16)silu_f(s[r]);
  }
}

// ---------------------------------------------------------------------------
// gemm2 MERGED: one grid of 8704 blocks.
//   bid <  256 : BOUNDARY tiles (t_base = bid/32*2048) - full meta/cache path
//   bid <  512 : cache-update scatter (tiny)
//   bid >= 512 : INTERIOR tiles (v11 path, t-major, batched B, (256,3))
// bnd+cache dispatch first and hide under the 8192 interior blocks,
// removing ~11us of serial kernel tail.
// ---------------------------------------------------------------------------
__global__ __launch_bounds__(256, 3) void gemm2_all(
    const float* __restrict__ x, const _Float16* __restrict__ hlin,
    const _Float16* __restrict__ w2f, const float* __restrict__ b2t,
    const float* __restrict__ cache, const int* __restrict__ cu_seqlens,
    const int* __restrict__ seq_idx, const int* __restrict__ cache_indices,
    const unsigned char* __restrict__ hi_u8, const int* __restrict__ hi_i32,
    float* __restrict__ out, float* __restrict__ outc) {
  __shared__ float xs[4][35 * 36];
  int bid = blockIdx.x, tid = threadIdx.x;
  int lane = tid & 63, wv = tid >> 6;
  int wr = wv >> 1, wc = wv & 1;
  int g = lane >> 4, c = lane & 15;
  float* myxs = xs[wv];

  if (bid >= 256 && bid < 512) {        // ---------- cache update ----------
    int idx = (bid - 256) * 256 + tid;
    int b = idx >> 13, d = (idx >> 2) & 2047, j = idx & 3;
    float val = cache[idx];
    if (j >= 1) {
      for (int i = 0; i < B_DIM; ++i) { // last-wins scatter semantics
        if (cache_indices[i] == b) {
          int L = cu_seqlens[i + 1] - cu_seqlens[i];
          int rel = L - (W_DIM - 1) + (j - 1);
          if (rel >= 0) {
            int tok = cu_seqlens[i] + rel;
            tok = max(0, min(T_DIM - 1, tok));
            val = x[(size_t)tok * D_DIM + d];
          } else {
            bool hi = (hi_u8[i] != 0) | (hi_i32[i] != 0);
            int slot = 4 + rel;
            slot = max(0, min(3, slot));
            val = hi ? cache[b * (D_DIM * W_DIM) + d * 4 + slot]
                     : cache[b * (D_DIM * W_DIM) + d * 4 + j];
          }
        }
      }
    }
    outc[idx] = val;
    return;
  }

  bool is_bnd = (bid < 256);
  int t_base, d_base;
  if (is_bnd) {
    t_base = (bid >> 5) * 2048;
    d_base = (bid & 31) * 64;
  } else {
    int ib = bid - 512;
    t_base = (ib >> 5) * 64;
    if ((t_base & 2047) == 0) return;   // boundary tiles handled above
    d_base = (ib & 31) * 64;
  }

  // stage wave slab: rows t_base+32wr-3 .. +31, cols d_base+32wc .. +32
  {
    int colbase = d_base + 32 * wc;
    int r8 = lane >> 3, c4 = (lane & 7) * 4;
#pragma unroll
    for (int p = 0; p < 5; ++p) {
      int r = p * 8 + r8;
      if (r < 35) {
        int gr = t_base + 32 * wr - 3 + r;
        gr = max(0, gr);                 // only binds for bnd t_base=0
        float4 v = *reinterpret_cast<const float4*>(
            x + (size_t)gr * D_DIM + colbase + c4);
        *reinterpret_cast<float4*>(&myxs[r * 36 + c4]) = v;
      }
    }
  }

  // resident A fragments
  const _Float16* a0p = hlin + (size_t)(t_base + 32 * wr + c) * GHD + 8 * g;
  const _Float16* a1p = hlin + (size_t)(t_base + 32 * wr + 16 + c) * GHD + 8 * g;
  f16x8 A00 = *reinterpret_cast<const f16x8*>(a0p);
  f16x8 A01 = *reinterpret_cast<const f16x8*>(a0p + 32);
  f16x8 A02 = *reinterpret_cast<const f16x8*>(a0p + 64);
  f16x8 A03 = *reinterpret_cast<const f16x8*>(a0p + 96);
  f16x8 A10 = *reinterpret_cast<const f16x8*>(a1p);
  f16x8 A11 = *reinterpret_cast<const f16x8*>(a1p + 32);
  f16x8 A12 = *reinterpret_cast<const f16x8*>(a1p + 64);
  f16x8 A13 = *reinterpret_cast<const f16x8*>(a1p + 96);

  // boundary metadata (only the 256 bnd blocks pay this)
  int meta[8];
  if (is_bnd) {
#pragma unroll
    for (int m = 0; m < 2; ++m)
#pragma unroll
      for (int r = 0; r < 4; ++r) {
        int t = t_base + 32 * wr + 16 * m + 4 * g + r;
        int s = seq_idx[t];
        int pos = t - cu_seqlens[s];
        int ci = cache_indices[s];
        int hi = (hi_u8[s] != 0) | (hi_i32[s] != 0);
        meta[m * 4 + r] = pos | (ci << 16) | (hi << 24);
      }
  }

  f32x4 oacc[2][2];
#pragma unroll
  for (int m = 0; m < 2; ++m) {
    oacc[m][0] = f32x4{0.f, 0.f, 0.f, 0.f};
    oacc[m][1] = f32x4{0.f, 0.f, 0.f, 0.f};
  }

  int df0 = (d_base >> 4) + 2 * wc;
  const _Float16* wbase = w2f + (size_t)df0 * 4 * 64 * 8 + (size_t)lane * 8;

#pragma unroll
  for (int w = 0; w < 4; ++w) {
    float bw0 = b2t[w * D_DIM + d_base + 32 * wc + c];
    float bw1 = b2t[w * D_DIM + d_base + 32 * wc + 16 + c];
    const _Float16* wp = wbase + (size_t)w * 128 * 4 * 64 * 8;
    f16x8 B00 = *reinterpret_cast<const f16x8*>(wp + 0 * 512);
    f16x8 B01 = *reinterpret_cast<const f16x8*>(wp + 1 * 512);
    f16x8 B02 = *reinterpret_cast<const f16x8*>(wp + 2 * 512);
    f16x8 B03 = *reinterpret_cast<const f16x8*>(wp + 3 * 512);
    f16x8 B10 = *reinterpret_cast<const f16x8*>(wp + 4 * 512);
    f16x8 B11 = *reinterpret_cast<const f16x8*>(wp + 5 * 512);
    f16x8 B12 = *reinterpret_cast<const f16x8*>(wp + 6 * 512);
    f16x8 B13 = *reinterpret_cast<const f16x8*>(wp + 7 * 512);

    f32x4 acc[2][2];
#pragma unroll
    for (int m = 0; m < 2; ++m) {
      acc[m][0] = f32x4{0.f, 0.f, 0.f, 0.f};
      acc[m][1] = f32x4{0.f, 0.f, 0.f, 0.f};
    }
    acc[0][0] = __builtin_amdgcn_mfma_f32_16x16x32_f16(A00, B00, acc[0][0], 0, 0, 0);
    acc[1][0] = __builtin_amdgcn_mfma_f32_16x16x32_f16(A10, B00, acc[1][0], 0, 0, 0);
    acc[0][1] = __builtin_amdgcn_mfma_f32_16x16x32_f16(A00, B10, acc[0][1], 0, 0, 0);
    acc[1][1] = __builtin_amdgcn_mfma_f32_16x16x32_f16(A10, B10, acc[1][1], 0, 0, 0);
    acc[0][0] = __builtin_amdgcn_mfma_f32_16x16x32_f16(A01, B01, acc[0][0], 0, 0, 0);
    acc[1][0] = __builtin_amdgcn_mfma_f32_16x16x32_f16(A11, B01, acc[1][0], 0, 0, 0);
    acc[0][1] = __builtin_amdgcn_mfma_f32_16x16x32_f16(A01, B11, acc[0][1], 0, 0, 0);
    acc[1][1] = __builtin_amdgcn_mfma_f32_16x16x32_f16(A11, B11, acc[1][1], 0, 0, 0);
    acc[0][0] = __builtin_amdgcn_mfma_f32_16x16x32_f16(A02, B02, acc[0][0], 0, 0, 0);
    acc[1][0] = __builtin_amdgcn_mfma_f32_16x16x32_f16(A12, B02, acc[1][0], 0, 0, 0);
    acc[0][1] = __builtin_amdgcn_mfma_f32_16x16x32_f16(A02, B12, acc[0][1], 0, 0, 0);
    acc[1][1] = __builtin_amdgcn_mfma_f32_16x16x32_f16(A12, B12, acc[1][1], 0, 0, 0);
    acc[0][0] = __builtin_amdgcn_mfma_f32_16x16x32_f16(A03, B03, acc[0][0], 0, 0, 0);
    acc[1][0] = __builtin_amdgcn_mfma_f32_16x16x32_f16(A13, B03, acc[1][0], 0, 0, 0);
    acc[0][1] = __builtin_amdgcn_mfma_f32_16x16x32_f16(A03, B13, acc[0][1], 0, 0, 0);
    acc[1][1] = __builtin_amdgcn_mfma_f32_16x16x32_f16(A13, B13, acc[1][1], 0, 0, 0);

    int o = 3 - w;
    if (!is_bnd) {
#pragma unroll
      for (int m = 0; m < 2; ++m)
#pragma unroll
        for (int r = 0; r < 4; ++r) {
          int rl = 16 * m + 4 * g + r;
          float c0 = myxs[(rl + 3 - o) * 36 + c];
          float c1 = myxs[(rl + 3 - o) * 36 + 16 + c];
          oacc[m][0][r] += (acc[m][0][r] + bw0) * c0;
          oacc[m][1][r] += (acc[m][1][r] + bw1) * c1;
        }
    } else {
#pragma unroll
      for (int m = 0; m < 2; ++m)
#pragma unroll
        for (int r = 0; r < 4; ++r) {
          int mt = meta[m * 4 + r];
          int pos = mt & 0xffff;
          int rl = 16 * m + 4 * g + r;
#pragma unroll
          for (int n = 0; n < 2; ++n) {
            int col = 32 * wc + 16 * n + c;
            float ctx;
            if (pos >= o) {
              ctx = myxs[(rl + 3 - o) * 36 + 16 * n + c];
            } else if ((mt >> 24) & 1) {
              int ci = (mt >> 16) & 0xff;
              ctx = cache[(size_t)ci * (D_DIM * W_DIM) +
                          (size_t)(d_base + col) * W_DIM + (4 + pos - o)];
            } else {
              ctx = 0.f;
            }
            float bw = (n == 0) ? bw0 : bw1;
            oacc[m][n][r] += (acc[m][n][r] + bw) * ctx;
          }
        }
    }
  }

#pragma unroll
  for (int m = 0; m < 2; ++m)
#pragma unroll
    for (int r = 0; r < 4; ++r) {
      int t = t_base + 32 * wr + 16 * m + 4 * g + r;
#pragma unroll
      for (int n = 0; n < 2; ++n) {
        int col = d_base + 32 * wc + 16 * n + c;
        out[(size_t)t * D_DIM + col] = silu_f(oacc[m][n][r]);
      }
    }
}

extern "C" void kernel_launch(void* const* d_in, const int* in_sizes, int n_in,
                              void* d_out, int out_size, void* d_ws, size_t ws_size,
                              hipStream_t stream) {
  const float* x     = (const float*)d_in[0];
  const float* gen   = (const float*)d_in[1];
  const float* w1    = (const float*)d_in[2];
  const float* w2    = (const float*)d_in[3];
  const float* b2    = (const float*)d_in[4];
  const float* cache = (const float*)d_in[5];
  const int* cu      = (const int*)d_in[6];
  const int* seq     = (const int*)d_in[7];
  const int* cidx    = (const int*)d_in[8];
  const unsigned char* hi8 = (const unsigned char*)d_in[9];
  const int* hi32          = (const int*)d_in[9];
  float* out = (float*)d_out;

  char* ws = (char*)d_ws;
  _Float16* w1f  = (_Float16*)(ws + WS_W1F);
  _Float16* w2f  = (_Float16*)(ws + WS_W2F);
  float*    b2t  = (float*)(ws + WS_B2T);
  _Float16* hlin = (_Float16*)(ws + WS_HLIN);

  prep_kernel<<<dim3(584), dim3(256), 0, stream>>>(w1, w2, b2, w1f, w2f, b2t);
  gemm1_kernel<<<dim3(1024), dim3(256), 0, stream>>>(gen, w1f, hlin);
  gemm2_all<<<dim3(8704), dim3(256), 0, stream>>>(
      x, hlin, w2f, b2t, cache, cu, seq, cidx, hi8, hi32,
      out, out + (size_t)T_DIM * D_DIM);
}